// Round 1
// baseline (425.131 us; speedup 1.0000x reference)
//
#include <hip/hip_runtime.h>

// Problem constants: B=4096 batches, D=100 features, T=100 timesteps, O=3 outputs.
#define NB 4096
#define ND 100
#define NT 100
#define NO 3
#define BPB 2                  // batches per block
#define THREADS 256            // 4 waves; 200 compute lanes active
#define NROW (BPB * NT)        // 200 rows per block

// Fused kernel: one thread per (b,t) row computes cur[t][0..2] entirely in
// registers (spike computed once, reused for 3 FMAs — no spike staging),
// then 6 lanes per block run the sequential leaky scan for the block's
// 2 batches from a tiny LDS cur tile.
//
// Rationale vs previous version: old kernel was MLP-bound (VALUBusy 9%,
// HBM 18%, occupancy 31% — 41KB LDS/block -> ~2 blocks/CU, ~4KB in flight
// vs ~20KB needed). Here LDS is 3.7KB, every lane issues 50 independent
// float4 loads, and the scan kernel + workspace round-trip are gone.
__global__ __launch_bounds__(THREADS) void fused_kernel(
    const float* __restrict__ x, const float* __restrict__ u,
    const float* __restrict__ W, const float* __restrict__ bias,
    const float* __restrict__ beta_p, const float* __restrict__ thr_p,
    float* __restrict__ out)
{
    __shared__ float4 W4[NO][ND / 4];      // 3 x 25 float4 = 1200 B
    __shared__ float  bs[NO];
    __shared__ float  curS[BPB][NT][NO];   // 2*100*3 floats = 2400 B

    const int tid = threadIdx.x;
    const int b0  = blockIdx.x * BPB;      // grid = NB/BPB = 2048, exact

    // Stage W ([3][100] row-major, 300 floats = 75 float4) and bias.
    if (tid < NO * (ND / 4)) {
        W4[tid / (ND / 4)][tid % (ND / 4)] = ((const float4*)W)[tid];
    }
    if (tid < NO) bs[tid] = bias[tid];
    __syncthreads();

    // Phase 1: cur[b][t][o] = bias[o] + sum_d (u<x) * W[o][d], one row/thread.
    if (tid < NROW) {
        const int lb = tid / NT;           // 0..1
        const int t  = tid - lb * NT;      // 0..99
        const size_t R = (size_t)(b0 + lb) * NT + t;   // global row b*100+t
        const float4* xr = (const float4*)(x + R * ND); // R*400B -> 16B aligned
        const float4* ur = (const float4*)(u + R * ND);
        float a0 = bs[0], a1 = bs[1], a2 = bs[2];
#pragma unroll
        for (int i = 0; i < ND / 4; ++i) {
            float4 xv = xr[i];
            float4 uv = ur[i];
            float4 w0 = W4[0][i];          // uniform index across wave -> broadcast
            float4 w1 = W4[1][i];
            float4 w2 = W4[2][i];
            float s;
            s = (uv.x < xv.x) ? 1.0f : 0.0f;
            a0 = fmaf(s, w0.x, a0); a1 = fmaf(s, w1.x, a1); a2 = fmaf(s, w2.x, a2);
            s = (uv.y < xv.y) ? 1.0f : 0.0f;
            a0 = fmaf(s, w0.y, a0); a1 = fmaf(s, w1.y, a1); a2 = fmaf(s, w2.y, a2);
            s = (uv.z < xv.z) ? 1.0f : 0.0f;
            a0 = fmaf(s, w0.z, a0); a1 = fmaf(s, w1.z, a1); a2 = fmaf(s, w2.z, a2);
            s = (uv.w < xv.w) ? 1.0f : 0.0f;
            a0 = fmaf(s, w0.w, a0); a1 = fmaf(s, w1.w, a1); a2 = fmaf(s, w2.w, a2);
        }
        curS[lb][t][0] = a0;
        curS[lb][t][1] = a1;
        curS[lb][t][2] = a2;
    }
    __syncthreads();

    // Phase 2: sequential leaky scan, one lane per (batch, output) = 6 lanes.
    // Nonlinear recurrence (threshold reset) -> must be serial over t.
    if (tid < BPB * NO) {
        const int lb = tid / NO;
        const int o  = tid - lb * NO;
        const int bo = (b0 + lb) * NO + o;            // column in [0, 12288)
        const float beta = beta_p[0];
        const float thr  = thr_p[0];
        float* mem_rec = out + (size_t)NT * NB * NO;
        float mem = 0.0f;
        for (int t = 0; t < NT; ++t) {
            float cv = curS[lb][t][o];
            // reset from PREVIOUS mem: heaviside(mem - thr) * thr
            float rsub = (mem > thr) ? thr : 0.0f;
            // match reference op order: ((beta*mem) + cur) - reset*thr, no FMA
            mem = __fadd_rn(__fadd_rn(__fmul_rn(beta, mem), cv), -rsub);
            out[(size_t)t * (NB * NO) + bo]     = (mem > thr) ? 1.0f : 0.0f;
            mem_rec[(size_t)t * (NB * NO) + bo] = mem;
        }
    }
}

extern "C" void kernel_launch(void* const* d_in, const int* in_sizes, int n_in,
                              void* d_out, int out_size, void* d_ws, size_t ws_size,
                              hipStream_t stream) {
    const float* x    = (const float*)d_in[0];   // [4096,100,100]
    const float* u    = (const float*)d_in[1];   // [4096,100,100]
    const float* W    = (const float*)d_in[2];   // [3,100]
    const float* bias = (const float*)d_in[3];   // [3]
    const float* beta = (const float*)d_in[4];   // scalar
    const float* thr  = (const float*)d_in[5];   // scalar
    float* out = (float*)d_out;

    fused_kernel<<<NB / BPB, THREADS, 0, stream>>>(x, u, W, bias, beta, thr, out);
}